// Round 4
// baseline (97.421 us; speedup 1.0000x reference)
//
#include <hip/hip_runtime.h>

// SparseConv1D on MI355X, round 3.
// out[b,o,l] = sum_{t,i} W[o,i,t] * x[b,i,l+tap_t] = 32 shifted GEMMs (MFMA 16x16x32 bf16).
// R3 vs R2 (inferred sconv ~27us vs ~15us floor; stall = __syncthreads vmcnt(0)
// draining the just-issued stage):
//  - AITER-style K-loop: raw s_barrier + manual s_waitcnt vmcnt(4) (vmcnt(0) only
//    at the last tap). B-window TRIPLE-buffered (staged 2 taps ahead -> waited
//    loads are 2 compute phases old), W double-buffered. Issue order per iter:
//    W(t+1) then B(t+2), so vmcnt(4) retires exactly {W(t),B(t)}.
//  - LDS = 3x16KB (B) + 2x8KB (W) = 64KB -> still 2 blocks/CU.
//  - XCD-aware block swizzle: XCD k gets batches {2k,2k+1} (1.25MB Xp slice per
//    4MB XCD-L2) -> staging hits L2 instead of L3.

#define B_    16
#define CIN   64
#define COUT  64
#define LEN   4096
#define PAD_LO 512
#define PAD_HI 256
#define LPAD  (LEN + PAD_LO + PAD_HI)   // 4864
#define NTAP  32

typedef float f32x4 __attribute__((ext_vector_type(4)));
typedef short bf16x8_s __attribute__((ext_vector_type(8)));
typedef __bf16 bf16x8_b __attribute__((ext_vector_type(8)));
typedef unsigned short u16x8 __attribute__((ext_vector_type(8)));

template <typename V>
static __device__ inline auto mfma_16x16x32_bf16(V a, V b, f32x4 c, int)
    -> decltype(__builtin_amdgcn_mfma_f32_16x16x32_bf16(a, b, c, 0, 0, 0)) {
  return __builtin_amdgcn_mfma_f32_16x16x32_bf16(a, b, c, 0, 0, 0);
}
template <typename V>
static __device__ inline f32x4 mfma_16x16x32_bf16(V a, V b, f32x4 c, long) {
  return __builtin_amdgcn_mfma_f32_16x16x32_bf16(
      __builtin_bit_cast(bf16x8_b, a), __builtin_bit_cast(bf16x8_b, b), c, 0, 0, 0);
}

static __device__ inline unsigned short f32_to_bf16_rne(float f) {
  unsigned int u = __builtin_bit_cast(unsigned int, f);
  u += 0x7fffu + ((u >> 16) & 1u);
  return (unsigned short)(u >> 16);
}

// async 16B/lane global->LDS; lds dest is the wave-uniform base (HW adds lane*16)
static __device__ inline void async_copy16(const void* g, void* l) {
  __builtin_amdgcn_global_load_lds((const __attribute__((address_space(1))) unsigned int*)g,
                                   (__attribute__((address_space(3))) unsigned int*)l, 16, 0, 0);
}

// ---------------- prep: x[b][i][l] fp32 -> Xp[b][lp][i] bf16 (padded) -------------
__global__ __launch_bounds__(256) void prep_x(const float* __restrict__ x,
                                              unsigned short* __restrict__ xp) {
  __shared__ float tile[64][65];
  const int b = blockIdx.y;
  const int lp0 = blockIdx.x * 64;
  const int tid = threadIdx.x;
  const bool data = (lp0 >= PAD_LO) && (lp0 < PAD_LO + LEN);
  if (data) {
    const int l0 = lp0 - PAD_LO;
#pragma unroll
    for (int it = 0; it < 4; ++it) {
      const int pidx = it * 256 + tid;
      const int il = pidx >> 4;          // channel
      const int lq = (pidx & 15) * 4;    // 4 consecutive l
      const float4 v = *(const float4*)&x[(size_t)(b * CIN + il) * LEN + l0 + lq];
      tile[lq + 0][il] = v.x;
      tile[lq + 1][il] = v.y;
      tile[lq + 2][il] = v.z;
      tile[lq + 3][il] = v.w;
    }
  }
  __syncthreads();
#pragma unroll
  for (int it = 0; it < 2; ++it) {
    const int pidx = it * 256 + tid;
    const int ll = pidx >> 3;
    const int i8 = (pidx & 7) * 8;
    u16x8 v = {0, 0, 0, 0, 0, 0, 0, 0};
    if (data) {
#pragma unroll
      for (int j = 0; j < 8; ++j) v[j] = f32_to_bf16_rne(tile[ll][i8 + j]);
    }
    *(u16x8*)&xp[(size_t)(b * LPAD + lp0 + ll) * CIN + i8] = v;
  }
}

// ------ prep: w[o][i][t] fp32 -> Wf[t][c][m][lane][8] bf16 (frag-major, 8KB/tap) ---
// A-frag content: W[o = 16m + (lane&15)][i = c*32 + (lane>>4)*8 + j][t]
__global__ __launch_bounds__(256) void prep_w(const float* __restrict__ w,
                                              unsigned short* __restrict__ wf) {
  const int e = blockIdx.x * 256 + threadIdx.x;  // < 32*2*4*64*8 = 131072
  const int j = e & 7;
  const int lane = (e >> 3) & 63;
  const int m = (e >> 9) & 3;
  const int c = (e >> 11) & 1;
  const int t = e >> 12;
  const int q = lane >> 4, r = lane & 15;
  const int o = m * 16 + r;
  const int i = c * 32 + q * 8 + j;
  wf[e] = f32_to_bf16_rne(w[(size_t)(o * CIN + i) * NTAP + t]);
}

// ---------------- main: 3-deep B / 2-deep W pipeline, raw barrier + vmcnt(4) ------
__global__ __launch_bounds__(256, 2) void sconv_main(const unsigned short* __restrict__ xp,
                                                     const unsigned short* __restrict__ wf,
                                                     float* __restrict__ out) {
  constexpr int TAP[NTAP] = {-512, -256, -128, -96, -64, -48, -32, -24, -16, -12, -8,
                             -6,   -4,   -3,   -2,  -1,  0,   1,   2,   3,   4,  6,
                             8,    12,   16,   24,  32,  48,  64,  96,  128, 256};
  __shared__ alignas(16) char bbuf[3][16384];  // B 128-row windows
  __shared__ alignas(16) char wbuf[2][8192];   // W_t frag-major

  const int id = blockIdx.x;
  const int b = (id & 7) * 2 + (id >> 8);      // XCD k <- batches {2k,2k+1}
  const int l0 = ((id >> 3) & 31) * 128;
  const int tid = threadIdx.x;
  const int wave = tid >> 6, lane = tid & 63;
  const int q = lane >> 4, r = lane & 15;
  const int oh = wave & 1, lh = wave >> 1;     // wave tile: 32o x 64l

  // B staging source offsets (bytes), XOR-swizzled: LDS chunk s holds global
  // chunk (row = s>>3, (s&7) ^ (row&7))
  int boff[4];
#pragma unroll
  for (int it = 0; it < 4; ++it) {
    const int s = it * 256 + tid;
    const int row = s >> 3, ch = s & 7;
    boff[it] = (row * 8 + (ch ^ (row & 7))) * 16;
  }

  const char* xbase = (const char*)xp + (size_t)(b * LPAD + l0 + PAD_LO) * (CIN * 2);
  const char* wbase = (const char*)wf;

  auto stageW = [&](int t, int p) {
    const char* wsrc = wbase + t * 8192;
#pragma unroll
    for (int it = 0; it < 2; ++it)
      async_copy16(wsrc + (it * 256 + wave * 64 + lane) * 16,
                   &wbuf[p][(it * 256 + wave * 64) * 16]);
  };
  auto stageB = [&](int t, int p) {
    const char* win = xbase + TAP[t] * (CIN * 2);
#pragma unroll
    for (int it = 0; it < 4; ++it)
      async_copy16(win + boff[it], &bbuf[p][(it * 256 + wave * 64) * 16]);
  };

  f32x4 acc[2][4] = {};

  // prologue issue order: W0, B0, B1  (oldest-first bookkeeping)
  stageW(0, 0);
  stageB(0, 0);
  stageB(1, 1);

#pragma unroll
  for (int t = 0; t < NTAP; ++t) {
    __builtin_amdgcn_sched_barrier(0);
    // retire exactly {W(t), B(t)}: newest allowed outstanding = B(t+1) (4 loads).
    // imm: vmcnt[3:0], exp[6:4]=7 (don't care), lgkm[11:8]=15 (don't care)
    if (t == NTAP - 1) __builtin_amdgcn_s_waitcnt(0x0F70);  // vmcnt(0)
    else               __builtin_amdgcn_s_waitcnt(0x0F74);  // vmcnt(4)
    __builtin_amdgcn_s_barrier();
    __builtin_amdgcn_sched_barrier(0);
    if (t + 1 < NTAP) stageW(t + 1, (t + 1) & 1);   // W before B: keeps vmcnt math
    if (t + 2 < NTAP) stageB(t + 2, (t + 2) % 3);
    __builtin_amdgcn_sched_barrier(0);

    const char* Bb = bbuf[t % 3];
    const char* Wb = wbuf[t & 1];
#pragma unroll
    for (int c = 0; c < 2; ++c) {
      bf16x8_s A[2], Bf[4];
#pragma unroll
      for (int m = 0; m < 2; ++m)
        A[m] = *(const bf16x8_s*)(Wb + (c * 256 + (oh * 2 + m) * 64 + lane) * 16);
#pragma unroll
      for (int n = 0; n < 4; ++n) {
        const int row = lh * 64 + n * 16 + r;
        Bf[n] = *(const bf16x8_s*)(Bb + (row * 8 + ((c * 4 + q) ^ (r & 7))) * 16);
      }
#pragma unroll
      for (int m = 0; m < 2; ++m)
#pragma unroll
        for (int n = 0; n < 4; ++n)
          acc[m][n] = mfma_16x16x32_bf16(A[m], Bf[n], acc[m][n], 0);
    }
  }

  // C/D layout (verified): col(l) = lane&15, row(o) = (lane>>4)*4 + reg
#pragma unroll
  for (int m = 0; m < 2; ++m)
#pragma unroll
    for (int n = 0; n < 4; ++n)
#pragma unroll
      for (int d = 0; d < 4; ++d) {
        const int o = oh * 32 + m * 16 + q * 4 + d;
        const int l = l0 + lh * 64 + n * 16 + r;
        out[(size_t)(b * COUT + o) * LEN + l] = acc[m][n][d];
      }
}

extern "C" void kernel_launch(void* const* d_in, const int* in_sizes, int n_in,
                              void* d_out, int out_size, void* d_ws, size_t ws_size,
                              hipStream_t stream) {
  const float* x = (const float*)d_in[0];        // [16][64][4096]
  const float* w = (const float*)d_in[1];        // [64][64][32]
  float* out = (float*)d_out;                    // [16][64][4096]

  unsigned short* xp = (unsigned short*)d_ws;                    // 16*4864*64 bf16 = 9.96 MB
  unsigned short* wfp = xp + (size_t)B_ * LPAD * CIN;            // 256 KB

  prep_x<<<dim3(LPAD / 64, B_), 256, 0, stream>>>(x, xp);
  prep_w<<<dim3((NTAP * 2 * 4 * 64 * 8) / 256), 256, 0, stream>>>(w, wfp);
  sconv_main<<<dim3(16 * 32), 256, 0, stream>>>(xp, wfp, out);
}

// Round 5
// 93.968 us; speedup vs baseline: 1.0368x; 1.0368x over previous
//
#include <hip/hip_runtime.h>

// SparseConv1D on MI355X, round 4.
// out[b,o,l] = sum_{t,i} W[o,i,t] * x[b,i,l+tap_t] = 32 shifted GEMMs (MFMA 16x16x32 bf16).
// R4 vs R2/R3 (R3 manual-vmcnt was neutral -> stall is LDS-read + staging BW, not latency):
//  - wave tile 64o x 64l (m4n4): reads/MFMA 0.75 -> 0.5; block tile 64o x 256l, grid 256.
//  - SLIDING-RING B buffer (512 rows, slot = row & 511): taps sorted ascending, stage only
//    the delta rows per tap (1024 rows/block total vs 8192 restaged) -> B staging 256->34 MB.
//    Ring groups 8-row-aligned so global_load_lds's lane-sequential LDS dest never wraps.
//    WAR-safe: delta(t+1) only overwrites slots of rows below window(t); alignment overlap
//    rows rewrite identical bytes.
//  - LDS: W dbuf 2x8KB at [0,16K) + ring 64KB at [16K,80K). __syncthreads per tap (R2
//    structure, proven; loads waited on are one full compute phase old).

#define B_    16
#define CIN   64
#define COUT  64
#define LEN   4096
#define PAD_LO 512
#define PAD_HI 256
#define LPAD  (LEN + PAD_LO + PAD_HI)   // 4864
#define NTAP  32

typedef float f32x4 __attribute__((ext_vector_type(4)));
typedef short bf16x8_s __attribute__((ext_vector_type(8)));
typedef __bf16 bf16x8_b __attribute__((ext_vector_type(8)));
typedef unsigned short u16x8 __attribute__((ext_vector_type(8)));

template <typename V>
static __device__ inline auto mfma_16x16x32_bf16(V a, V b, f32x4 c, int)
    -> decltype(__builtin_amdgcn_mfma_f32_16x16x32_bf16(a, b, c, 0, 0, 0)) {
  return __builtin_amdgcn_mfma_f32_16x16x32_bf16(a, b, c, 0, 0, 0);
}
template <typename V>
static __device__ inline f32x4 mfma_16x16x32_bf16(V a, V b, f32x4 c, long) {
  return __builtin_amdgcn_mfma_f32_16x16x32_bf16(
      __builtin_bit_cast(bf16x8_b, a), __builtin_bit_cast(bf16x8_b, b), c, 0, 0, 0);
}

static __device__ inline unsigned short f32_to_bf16_rne(float f) {
  unsigned int u = __builtin_bit_cast(unsigned int, f);
  u += 0x7fffu + ((u >> 16) & 1u);
  return (unsigned short)(u >> 16);
}

// async 16B/lane global->LDS; lds dest is the wave-uniform base (HW adds lane*16)
static __device__ inline void async_copy16(const void* g, void* l) {
  __builtin_amdgcn_global_load_lds((const __attribute__((address_space(1))) unsigned int*)g,
                                   (__attribute__((address_space(3))) unsigned int*)l, 16, 0, 0);
}

// ---------------- prep: x[b][i][l] fp32 -> Xp[b][lp][i] bf16 (padded) -------------
__global__ __launch_bounds__(256) void prep_x(const float* __restrict__ x,
                                              unsigned short* __restrict__ xp) {
  __shared__ float tile[64][65];
  const int b = blockIdx.y;
  const int lp0 = blockIdx.x * 64;
  const int tid = threadIdx.x;
  const bool data = (lp0 >= PAD_LO) && (lp0 < PAD_LO + LEN);
  if (data) {
    const int l0 = lp0 - PAD_LO;
#pragma unroll
    for (int it = 0; it < 4; ++it) {
      const int pidx = it * 256 + tid;
      const int il = pidx >> 4;          // channel
      const int lq = (pidx & 15) * 4;    // 4 consecutive l
      const float4 v = *(const float4*)&x[(size_t)(b * CIN + il) * LEN + l0 + lq];
      tile[lq + 0][il] = v.x;
      tile[lq + 1][il] = v.y;
      tile[lq + 2][il] = v.z;
      tile[lq + 3][il] = v.w;
    }
  }
  __syncthreads();
#pragma unroll
  for (int it = 0; it < 2; ++it) {
    const int pidx = it * 256 + tid;
    const int ll = pidx >> 3;
    const int i8 = (pidx & 7) * 8;
    u16x8 v = {0, 0, 0, 0, 0, 0, 0, 0};
    if (data) {
#pragma unroll
      for (int j = 0; j < 8; ++j) v[j] = f32_to_bf16_rne(tile[ll][i8 + j]);
    }
    *(u16x8*)&xp[(size_t)(b * LPAD + lp0 + ll) * CIN + i8] = v;
  }
}

// ------ prep: w[o][i][t] fp32 -> Wf[t][c][m][lane][8] bf16 (frag-major, 8KB/tap) ---
// A-frag content: W[o = 16m + (lane&15)][i = c*32 + (lane>>4)*8 + j][t]
__global__ __launch_bounds__(256) void prep_w(const float* __restrict__ w,
                                              unsigned short* __restrict__ wf) {
  const int e = blockIdx.x * 256 + threadIdx.x;  // < 32*2*4*64*8 = 131072
  const int j = e & 7;
  const int lane = (e >> 3) & 63;
  const int m = (e >> 9) & 3;
  const int c = (e >> 11) & 1;
  const int t = e >> 12;
  const int q = lane >> 4, r = lane & 15;
  const int o = m * 16 + r;
  const int i = c * 32 + q * 8 + j;
  wf[e] = f32_to_bf16_rne(w[(size_t)(o * CIN + i) * NTAP + t]);
}

// ---------------- main: sliding ring + m4n4, one __syncthreads per tap ------------
__global__ __launch_bounds__(256, 2) void sconv_main(const unsigned short* __restrict__ xp,
                                                     const unsigned short* __restrict__ wf,
                                                     float* __restrict__ out) {
  constexpr int TAP[NTAP] = {-512, -256, -128, -96, -64, -48, -32, -24, -16, -12, -8,
                             -6,   -4,   -3,   -2,  -1,  0,   1,   2,   3,   4,  6,
                             8,    12,   16,   24,  32,  48,  64,  96,  128, 256};
  __shared__ alignas(16) char smem[81920];  // [0,16K): W dbuf; [16K,80K): ring 512 rows x 128B

  const int id = blockIdx.x;
  const int b = id >> 4;
  const int l0 = (id & 15) * 256;
  const int lb = l0 + PAD_LO;              // absolute padded base row, multiple of 256
  const int tid = threadIdx.x;
  const int wv = tid >> 6, lane = tid & 63;
  const int q = lane >> 4, r = lane & 15;

  const char* xbase = (const char*)xp + ((size_t)b * LPAD + lb) * (CIN * 2);
  const char* wbase = (const char*)wf;

  auto stageW = [&](int t) {
    const char* src = wbase + t * 8192;
    char* dst = smem + (t & 1) * 8192;
#pragma unroll
    for (int it = 0; it < 2; ++it)
      async_copy16(src + (it * 256 + wv * 64 + lane) * 16,
                   dst + (it * 256 + wv * 64) * 16);
  };
  // stage relative rows [a0, a0 + 8*ng) into the ring; a0 must be 8-aligned.
  // XOR swizzle: LDS[slot][ch'] = G[row][ch' ^ (row&7)], ch' = lane&7, row = a0+8g+(lane>>3)
  auto stageB = [&](int a0, int ng) {
    for (int g = wv; g < ng; g += 4) {
      const int ra = a0 + g * 8 + (lane >> 3);
      const int ch = (lane & 7) ^ (ra & 7);
      const int sb = (lb + a0 + g * 8) & 511;       // 8-aligned -> group never wraps
      async_copy16(xbase + (ptrdiff_t)ra * 128 + ch * 16, smem + 16384 + sb * 128);
    }
  };

  f32x4 acc[4][4] = {};

  stageW(0);
  stageB(-512, 32);   // full window for tap 0

#pragma unroll
  for (int t = 0; t < NTAP; ++t) {
    __syncthreads();                     // buf staged one tap ago is ready
    if (t + 1 < NTAP) {
      stageW(t + 1);
      const int dstart = TAP[t] + 256;   // first new row for window t+1
      const int dend = TAP[t + 1] + 256; // one past last
      const int a0 = dstart & ~7;        // align down (restages <=7 identical rows: benign)
      stageB(a0, (dend - a0 + 7) >> 3);
    }
    __builtin_amdgcn_sched_barrier(0);   // pin staging above compute

    const int e = (TAP[t] + r) & 7;      // row&7 for this lane (lb,64wv,16n all ==0 mod 8)
    int baddr[4];
#pragma unroll
    for (int n = 0; n < 4; ++n) {
      const int slot = (lb + TAP[t] + wv * 64 + 16 * n + r) & 511;
      baddr[n] = 16384 + slot * 128 + ((q ^ e) << 4);   // c=0 chunk; c=1 is ^64
    }
#pragma unroll
    for (int c = 0; c < 2; ++c) {
      bf16x8_s A[4], Bf[4];
#pragma unroll
      for (int m = 0; m < 4; ++m)
        A[m] = *(const bf16x8_s*)(smem + (t & 1) * 8192 + (c * 4 + m) * 1024 + lane * 16);
#pragma unroll
      for (int n = 0; n < 4; ++n)
        Bf[n] = *(const bf16x8_s*)(smem + (baddr[n] ^ (c << 6)));
#pragma unroll
      for (int m = 0; m < 4; ++m)
#pragma unroll
        for (int n = 0; n < 4; ++n)
          acc[m][n] = mfma_16x16x32_bf16(A[m], Bf[n], acc[m][n], 0);
    }
  }

  // C/D layout (verified): col(l) = lane&15, row(o) = (lane>>4)*4 + reg
#pragma unroll
  for (int m = 0; m < 4; ++m)
#pragma unroll
    for (int n = 0; n < 4; ++n)
#pragma unroll
      for (int d = 0; d < 4; ++d) {
        const int o = 16 * m + 4 * q + d;
        const int l = l0 + wv * 64 + 16 * n + r;
        out[((size_t)b * COUT + o) * LEN + l] = acc[m][n][d];
      }
}

extern "C" void kernel_launch(void* const* d_in, const int* in_sizes, int n_in,
                              void* d_out, int out_size, void* d_ws, size_t ws_size,
                              hipStream_t stream) {
  const float* x = (const float*)d_in[0];        // [16][64][4096]
  const float* w = (const float*)d_in[1];        // [64][64][32]
  float* out = (float*)d_out;                    // [16][64][4096]

  unsigned short* xp = (unsigned short*)d_ws;                    // 16*4864*64 bf16 = 9.96 MB
  unsigned short* wfp = xp + (size_t)B_ * LPAD * CIN;            // 256 KB

  prep_x<<<dim3(LPAD / 64, B_), 256, 0, stream>>>(x, xp);
  prep_w<<<dim3((NTAP * 2 * 4 * 64 * 8) / 256), 256, 0, stream>>>(w, wfp);
  sconv_main<<<dim3(B_ * 16), 256, 0, stream>>>(xp, wfp, out);
}

// Round 6
// 92.501 us; speedup vs baseline: 1.0532x; 1.0158x over previous
//
#include <hip/hip_runtime.h>

// SparseConv1D on MI355X, round 5.
// out[b,o,l] = sum_{t,i} W[o,i,t] * x[b,i,l+tap_t] = 32 shifted GEMMs (MFMA 16x16x32 bf16).
// R5 vs R4 (R4 = R2 exactly: traffic halved but occupancy halved - confounded):
//  - K-SPLIT waves: wave (lh,ch) does 64o x 64l x 32i (m4n4 single-c): 8 ds_reads per
//    16 MFMA (0.5) at block tile 64o x 128l -> grid 512, 2 blocks/CU, 8 waves/CU
//    (R2 TLP + R4 traffic). c-halves reduced through LDS at the end.
//  - Sliding ring kept, 512 rows x 128B (ltile 128 + max tap gap 256 + slack; WAR-safe
//    since gap<=384): B staging 57 MB total. W dbuf 2x8KB staged 1 tap ahead.
//  - LDS 80KB = exactly 2 blocks/CU. __syncthreads per tap (R2 proven; R3 showed more
//    slack is not the lever).

#define B_    16
#define CIN   64
#define COUT  64
#define LEN   4096
#define PAD_LO 512
#define PAD_HI 256
#define LPAD  (LEN + PAD_LO + PAD_HI)   // 4864
#define NTAP  32

typedef float f32x4 __attribute__((ext_vector_type(4)));
typedef short bf16x8_s __attribute__((ext_vector_type(8)));
typedef __bf16 bf16x8_b __attribute__((ext_vector_type(8)));
typedef unsigned short u16x8 __attribute__((ext_vector_type(8)));

template <typename V>
static __device__ inline auto mfma_16x16x32_bf16(V a, V b, f32x4 c, int)
    -> decltype(__builtin_amdgcn_mfma_f32_16x16x32_bf16(a, b, c, 0, 0, 0)) {
  return __builtin_amdgcn_mfma_f32_16x16x32_bf16(a, b, c, 0, 0, 0);
}
template <typename V>
static __device__ inline f32x4 mfma_16x16x32_bf16(V a, V b, f32x4 c, long) {
  return __builtin_amdgcn_mfma_f32_16x16x32_bf16(
      __builtin_bit_cast(bf16x8_b, a), __builtin_bit_cast(bf16x8_b, b), c, 0, 0, 0);
}

static __device__ inline unsigned short f32_to_bf16_rne(float f) {
  unsigned int u = __builtin_bit_cast(unsigned int, f);
  u += 0x7fffu + ((u >> 16) & 1u);
  return (unsigned short)(u >> 16);
}

// async 16B/lane global->LDS; lds dest is the wave-uniform base (HW adds lane*16)
static __device__ inline void async_copy16(const void* g, void* l) {
  __builtin_amdgcn_global_load_lds((const __attribute__((address_space(1))) unsigned int*)g,
                                   (__attribute__((address_space(3))) unsigned int*)l, 16, 0, 0);
}

// ---------------- prep: x[b][i][l] fp32 -> Xp[b][lp][i] bf16 (padded) -------------
__global__ __launch_bounds__(256) void prep_x(const float* __restrict__ x,
                                              unsigned short* __restrict__ xp) {
  __shared__ float tile[64][65];
  const int b = blockIdx.y;
  const int lp0 = blockIdx.x * 64;
  const int tid = threadIdx.x;
  const bool data = (lp0 >= PAD_LO) && (lp0 < PAD_LO + LEN);
  if (data) {
    const int l0 = lp0 - PAD_LO;
#pragma unroll
    for (int it = 0; it < 4; ++it) {
      const int pidx = it * 256 + tid;
      const int il = pidx >> 4;          // channel
      const int lq = (pidx & 15) * 4;    // 4 consecutive l
      const float4 v = *(const float4*)&x[(size_t)(b * CIN + il) * LEN + l0 + lq];
      tile[lq + 0][il] = v.x;
      tile[lq + 1][il] = v.y;
      tile[lq + 2][il] = v.z;
      tile[lq + 3][il] = v.w;
    }
  }
  __syncthreads();
#pragma unroll
  for (int it = 0; it < 2; ++it) {
    const int pidx = it * 256 + tid;
    const int ll = pidx >> 3;
    const int i8 = (pidx & 7) * 8;
    u16x8 v = {0, 0, 0, 0, 0, 0, 0, 0};
    if (data) {
#pragma unroll
      for (int j = 0; j < 8; ++j) v[j] = f32_to_bf16_rne(tile[ll][i8 + j]);
    }
    *(u16x8*)&xp[(size_t)(b * LPAD + lp0 + ll) * CIN + i8] = v;
  }
}

// ------ prep: w[o][i][t] fp32 -> Wf[t][c][m][lane][8] bf16 (frag-major, 8KB/tap) ---
// A-frag content: W[o = 16m + (lane&15)][i = c*32 + (lane>>4)*8 + j][t]
__global__ __launch_bounds__(256) void prep_w(const float* __restrict__ w,
                                              unsigned short* __restrict__ wf) {
  const int e = blockIdx.x * 256 + threadIdx.x;  // < 32*2*4*64*8 = 131072
  const int j = e & 7;
  const int lane = (e >> 3) & 63;
  const int m = (e >> 9) & 3;
  const int c = (e >> 11) & 1;
  const int t = e >> 12;
  const int q = lane >> 4, r = lane & 15;
  const int o = m * 16 + r;
  const int i = c * 32 + q * 8 + j;
  wf[e] = f32_to_bf16_rne(w[(size_t)(o * CIN + i) * NTAP + t]);
}

// ------------- main: K-split m4n4 waves + sliding ring, sync per tap -------------
__global__ __launch_bounds__(256, 2) void sconv_main(const unsigned short* __restrict__ xp,
                                                     const unsigned short* __restrict__ wf,
                                                     float* __restrict__ out) {
  constexpr int TAP[NTAP] = {-512, -256, -128, -96, -64, -48, -32, -24, -16, -12, -8,
                             -6,   -4,   -3,   -2,  -1,  0,   1,   2,   3,   4,  6,
                             8,    12,   16,   24,  32,  48,  64,  96,  128, 256};
  __shared__ alignas(16) char smem[81920];  // [0,64K): ring 512 rows x 128B; [64K,80K): W dbuf

  const int id = blockIdx.x;
  const int b = (id & 7) * 2 + ((id >> 3) & 1);   // XCD k <- batches {2k,2k+1}
  const int l0 = (id >> 4) * 128;                 // 32 l-tiles
  const int lb = l0 + PAD_LO;                     // absolute padded base row (mult of 128)
  const int tid = threadIdx.x;
  const int wv = tid >> 6, lane = tid & 63;
  const int q = lane >> 4, r = lane & 15;
  const int lh = wv & 1, ch = wv >> 1;            // wave: l-half lh, i-half ch

  const char* xbase = (const char*)xp + ((size_t)b * LPAD + lb) * (CIN * 2);
  const char* wbase = (const char*)wf;

  auto stageW = [&](int t) {
    const char* src = wbase + t * 8192;
    char* dst = smem + 65536 + (t & 1) * 8192;
#pragma unroll
    for (int it = 0; it < 2; ++it)
      async_copy16(src + (it * 256 + wv * 64 + lane) * 16,
                   dst + (it * 256 + wv * 64) * 16);
  };
  // stage relative rows [a0, a0+8*ng) into ring; a0 8-aligned.
  // LDS[slot][ch'] = G[row][ch' ^ (row&7)]
  auto stageB = [&](int a0, int ng) {
    for (int g = wv; g < ng; g += 4) {
      const int ra = a0 + g * 8 + (lane >> 3);
      const int cs = (lane & 7) ^ (ra & 7);
      const int sb = (lb + a0 + g * 8) & 511;      // 8-aligned group, never wraps
      async_copy16(xbase + (ptrdiff_t)ra * 128 + cs * 16, smem + sb * 128);
    }
  };

  f32x4 acc[4][4] = {};

  // prologue: W0 + window(0) rows [-512,-384)
  stageW(0);
  stageB(-512, 16);

#pragma unroll
  for (int t = 0; t < NTAP; ++t) {
    __syncthreads();                    // drains stages issued at iter t-1 (1 tap slack)
    if (t + 1 < NTAP) {
      stageW(t + 1);                    // buf (t+1)&1: last read at t-1, barrier passed
      const int dstart = TAP[t] + 128;  // delta rows for window t+1
      const int dend = TAP[t + 1] + 128;
      const int a0 = dstart & ~7;       // align down: <=7 identical-rewrite rows, benign
      stageB(a0, (dend - a0 + 7) >> 3);
    }
    __builtin_amdgcn_sched_barrier(0);  // pin staging issue above compute

    const int e = (TAP[t] + r) & 7;     // == row&7 for this lane's B rows
    const char* Wb = smem + 65536 + (t & 1) * 8192 + ch * 4096;
    bf16x8_s A[4], Bf[4];
#pragma unroll
    for (int m = 0; m < 4; ++m)
      A[m] = *(const bf16x8_s*)(Wb + m * 1024 + lane * 16);
#pragma unroll
    for (int n = 0; n < 4; ++n) {
      const int slot = (lb + TAP[t] + lh * 64 + 16 * n + r) & 511;
      Bf[n] = *(const bf16x8_s*)(smem + slot * 128 + (((ch * 4 + q) ^ e) << 4));
    }
#pragma unroll
    for (int m = 0; m < 4; ++m)
#pragma unroll
      for (int n = 0; n < 4; ++n)
        acc[m][n] = mfma_16x16x32_bf16(A[m], Bf[n], acc[m][n], 0);
  }

  // ---- reduce the two i-halves through LDS (ring area is dead now) ----
  __syncthreads();
  if (ch == 1) {
#pragma unroll
    for (int m = 0; m < 4; ++m)
#pragma unroll
      for (int n = 0; n < 4; ++n)
        *(f32x4*)(smem + lh * 16384 + ((m * 4 + n) * 64 + lane) * 16) = acc[m][n];
  }
  __syncthreads();
  if (ch == 0) {
#pragma unroll
    for (int m = 0; m < 4; ++m)
#pragma unroll
      for (int n = 0; n < 4; ++n) {
        const f32x4 other = *(const f32x4*)(smem + lh * 16384 + ((m * 4 + n) * 64 + lane) * 16);
        const f32x4 v = acc[m][n] + other;
        // C/D layout (verified): col(l) = lane&15, row(o) = (lane>>4)*4 + reg
#pragma unroll
        for (int d = 0; d < 4; ++d) {
          const int o = 16 * m + 4 * q + d;
          const int l = l0 + lh * 64 + 16 * n + r;
          out[((size_t)b * COUT + o) * LEN + l] = v[d];
        }
      }
  }
}

extern "C" void kernel_launch(void* const* d_in, const int* in_sizes, int n_in,
                              void* d_out, int out_size, void* d_ws, size_t ws_size,
                              hipStream_t stream) {
  const float* x = (const float*)d_in[0];        // [16][64][4096]
  const float* w = (const float*)d_in[1];        // [64][64][32]
  float* out = (float*)d_out;                    // [16][64][4096]

  unsigned short* xp = (unsigned short*)d_ws;                    // 16*4864*64 bf16 = 9.96 MB
  unsigned short* wfp = xp + (size_t)B_ * LPAD * CIN;            // 256 KB

  prep_x<<<dim3(LPAD / 64, B_), 256, 0, stream>>>(x, xp);
  prep_w<<<dim3((NTAP * 2 * 4 * 64 * 8) / 256), 256, 0, stream>>>(w, wfp);
  sconv_main<<<dim3(16 * 32), 256, 0, stream>>>(xp, wfp, out);
}